// Round 1
// baseline (488.322 us; speedup 1.0000x reference)
//
#include <hip/hip_runtime.h>

// Problem constants
#define NPX   131072      // B*H*W = 32*64*64 pixels
#define CHN   128         // NUM_HIDDENS
#define HWN   4096        // H*W
#define EMB   64
#define NCODE 512
#define DECN  16777216    // 32*128*4096

// ws layout (bytes)
#define WS_HIST 0         // 512 * u32
#define WS_LOSS 2048      // 1 * f32
#define WS_CC   4096      // 512 * f32
#define WS_PWT  8192      // 128*64 f32 (pre_w transposed, 32 KB)
#define WS_IDX  40960     // 131072 * i32 (512 KB)

// --- prep: transpose pre_w to [c][d] for contiguous uniform s_loads;
//     cc[k] = sum_d cb[k][d]^2 replicating numpy pairwise-8 order, unfused.
__global__ __launch_bounds__(512) void vq_prep(const float* __restrict__ preW,
                                               const float* __restrict__ cb,
                                               float* __restrict__ preWT,
                                               float* __restrict__ cc) {
  int t = threadIdx.x;
  for (int i = t; i < CHN * EMB; i += 512) {
    int c = i >> 6, d = i & 63;
    preWT[i] = preW[d * CHN + c];   // preW is [64][128]
  }
  if (t < NCODE) {
    const float* row = cb + t * EMB;
    float r[8];
#pragma unroll
    for (int j = 0; j < 8; ++j) r[j] = __fmul_rn(row[j], row[j]);
#pragma unroll
    for (int b = 1; b < 8; ++b)
#pragma unroll
      for (int j = 0; j < 8; ++j)
        r[j] = __fadd_rn(r[j], __fmul_rn(row[b * 8 + j], row[b * 8 + j]));
    cc[t] = __fadd_rn(__fadd_rn(__fadd_rn(r[0], r[1]), __fadd_rn(r[2], r[3])),
                      __fadd_rn(__fadd_rn(r[4], r[5]), __fadd_rn(r[6], r[7])));
  }
}

// --- main: per-thread pixel. pre-conv (z[64] in VGPRs), argmin over 512 codes,
//     loss partial + histogram + index outputs.
__global__ __launch_bounds__(256) void vq_main(const float* __restrict__ A,
                                               const float* __restrict__ preWT,
                                               const float* __restrict__ preB,
                                               const float* __restrict__ cb,
                                               const float* __restrict__ cc,
                                               float* __restrict__ outIdx,
                                               int* __restrict__ wsIdx,
                                               float* __restrict__ lossAcc,
                                               unsigned int* __restrict__ hist) {
  int p = blockIdx.x * 256 + threadIdx.x;
  int b = p >> 12, hw = p & 4095;
  const float* Ab = A + (size_t)b * CHN * HWN + hw;

  // pre-conv: z[d] = sum_c A[b,c,hw] * preW[d,c]  (sequential, unfused like np.einsum)
  float z[64];
#pragma unroll
  for (int d = 0; d < 64; ++d) z[d] = 0.f;
  for (int c = 0; c < CHN; ++c) {
    float a = Ab[(size_t)c * HWN];          // coalesced: consecutive lanes -> consecutive hw
    const float* w = preWT + c * EMB;       // wave-uniform -> s_load
#pragma unroll
    for (int d = 0; d < 64; ++d) z[d] = __fadd_rn(z[d], __fmul_rn(a, w[d]));
  }
#pragma unroll
  for (int d = 0; d < 64; ++d) z[d] = __fadd_rn(z[d], preB[d]);

  // zz = sum z^2, numpy pairwise-8 order, unfused
  float r[8];
#pragma unroll
  for (int j = 0; j < 8; ++j) r[j] = __fmul_rn(z[j], z[j]);
#pragma unroll
  for (int bb = 1; bb < 8; ++bb)
#pragma unroll
    for (int j = 0; j < 8; ++j)
      r[j] = __fadd_rn(r[j], __fmul_rn(z[bb * 8 + j], z[bb * 8 + j]));
  float zz = __fadd_rn(__fadd_rn(__fadd_rn(r[0], r[1]), __fadd_rn(r[2], r[3])),
                       __fadd_rn(__fadd_rn(r[4], r[5]), __fadd_rn(r[6], r[7])));

  // search: dist = fl(fl(zz + cc[k]) - 2*dot)   (2*dot is exact)
  float best = 3.4e38f;
  int bidx = 0;
  for (int k = 0; k < NCODE; ++k) {
    const float* crow = cb + (k << 6);      // wave-uniform -> s_load
    float d0 = 0.f, d1 = 0.f, d2 = 0.f, d3 = 0.f;
#pragma unroll
    for (int dd = 0; dd < 64; dd += 4) {
      d0 = fmaf(crow[dd + 0], z[dd + 0], d0);
      d1 = fmaf(crow[dd + 1], z[dd + 1], d1);
      d2 = fmaf(crow[dd + 2], z[dd + 2], d2);
      d3 = fmaf(crow[dd + 3], z[dd + 3], d3);
    }
    float dot = (d0 + d1) + (d2 + d3);
    float dist = __fadd_rn(__fadd_rn(zz, cc[k]), -2.0f * dot);
    if (dist < best) { best = dist; bidx = k; }   // strict < : first-min tie-break like np.argmin
  }

  // loss partial: sum (q - z)^2 ; loss = 1.25 * mean (e and q latent losses are equal in value)
  const float4* q4 = (const float4*)(cb + (bidx << 6));
  float ls = 0.f;
#pragma unroll
  for (int i = 0; i < 16; ++i) {
    float4 q = q4[i];
    float e;
    e = __fsub_rn(q.x, z[4 * i + 0]); ls = fmaf(e, e, ls);
    e = __fsub_rn(q.y, z[4 * i + 1]); ls = fmaf(e, e, ls);
    e = __fsub_rn(q.z, z[4 * i + 2]); ls = fmaf(e, e, ls);
    e = __fsub_rn(q.w, z[4 * i + 3]); ls = fmaf(e, e, ls);
  }
#pragma unroll
  for (int off = 32; off; off >>= 1) ls += __shfl_xor(ls, off, 64);
  if ((threadIdx.x & 63) == 0) atomicAdd(lossAcc, ls);
  atomicAdd(&hist[bidx], 1u);
  wsIdx[p] = bidx;
  outIdx[p] = (float)bidx;
}

// --- decode: out[b,o,hw] = sum_d q[d] * postW[o,d] + postB[o]
__global__ __launch_bounds__(256) void vq_decode(const float* __restrict__ cb,
                                                 const int* __restrict__ wsIdx,
                                                 const float* __restrict__ postW,
                                                 const float* __restrict__ postB,
                                                 float* __restrict__ dec) {
  int p = blockIdx.x * 256 + threadIdx.x;
  int b = p >> 12, hw = p & 4095;
  int k = wsIdx[p];
  float q[64];
  const float4* q4 = (const float4*)(cb + (k << 6));
#pragma unroll
  for (int i = 0; i < 16; ++i) {
    float4 v = q4[i];
    q[4 * i + 0] = v.x; q[4 * i + 1] = v.y; q[4 * i + 2] = v.z; q[4 * i + 3] = v.w;
  }
  float* out = dec + (size_t)b * CHN * HWN + hw;
  for (int o = 0; o < CHN; ++o) {
    const float* w = postW + o * EMB;       // wave-uniform -> s_load
    float a0 = 0.f, a1 = 0.f, a2 = 0.f, a3 = 0.f;
#pragma unroll
    for (int dd = 0; dd < 64; dd += 4) {
      a0 = fmaf(q[dd + 0], w[dd + 0], a0);
      a1 = fmaf(q[dd + 1], w[dd + 1], a1);
      a2 = fmaf(q[dd + 2], w[dd + 2], a2);
      a3 = fmaf(q[dd + 3], w[dd + 3], a3);
    }
    out[(size_t)o * HWN] = ((a0 + a1) + (a2 + a3)) + postB[o];  // coalesced per o
  }
}

// --- finalize: loss scalar + perplexity
__global__ __launch_bounds__(512) void vq_final(const unsigned int* __restrict__ hist,
                                                const float* __restrict__ lossAcc,
                                                float* __restrict__ outLoss,
                                                float* __restrict__ outPerp) {
  __shared__ float sred[8];
  int t = threadIdx.x;
  float c = (float)hist[t];
  float pavg = c * (1.0f / 131072.0f);
  float term = pavg * logf(pavg + 1e-10f);
#pragma unroll
  for (int off = 32; off; off >>= 1) term += __shfl_xor(term, off, 64);
  if ((t & 63) == 0) sred[t >> 6] = term;
  __syncthreads();
  if (t == 0) {
    float s = 0.f;
    for (int i = 0; i < 8; ++i) s += sred[i];
    *outPerp = expf(-s);
    *outLoss = 1.25f * (*lossAcc) * (1.0f / 8388608.0f);
  }
}

extern "C" void kernel_launch(void* const* d_in, const int* in_sizes, int n_in,
                              void* d_out, int out_size, void* d_ws, size_t ws_size,
                              hipStream_t stream) {
  const float* A     = (const float*)d_in[0];
  const float* preW  = (const float*)d_in[1];
  const float* preB  = (const float*)d_in[2];
  const float* cb    = (const float*)d_in[3];
  const float* postW = (const float*)d_in[4];
  const float* postB = (const float*)d_in[5];
  float* out = (float*)d_out;

  char* ws = (char*)d_ws;
  unsigned int* hist = (unsigned int*)(ws + WS_HIST);
  float* lossAcc = (float*)(ws + WS_LOSS);
  float* cc      = (float*)(ws + WS_CC);
  float* preWT   = (float*)(ws + WS_PWT);
  int* wsIdx     = (int*)(ws + WS_IDX);

  hipMemsetAsync(ws, 0, 2052, stream);  // zero hist + loss accumulator
  vq_prep<<<1, 512, 0, stream>>>(preW, cb, preWT, cc);
  vq_main<<<NPX / 256, 256, 0, stream>>>(A, preWT, preB, cb, cc,
                                         out + 16777218, wsIdx, lossAcc, hist);
  vq_decode<<<NPX / 256, 256, 0, stream>>>(cb, wsIdx, postW, postB, out + 1);
  vq_final<<<1, 512, 0, stream>>>(hist, lossAcc, out, out + 16777217);
}